// Round 4
// baseline (154.850 us; speedup 1.0000x reference)
//
#include <hip/hip_runtime.h>
#include <hip/hip_bf16.h>

typedef float f32x4 __attribute__((ext_vector_type(4)));
typedef float f32x16 __attribute__((ext_vector_type(16)));
typedef __bf16 bf16x8 __attribute__((ext_vector_type(8)));
typedef __bf16 bf16x4 __attribute__((ext_vector_type(4)));

#define MFMA(a, b, c) __builtin_amdgcn_mfma_f32_16x16x32_bf16(a, b, c, 0, 0, 0)
#define MFMA32(a, b, c) __builtin_amdgcn_mfma_f32_32x32x16_bf16(a, b, c, 0, 0, 0)
#define AS1 __attribute__((address_space(1)))
#define AS3 __attribute__((address_space(3)))

__device__ __forceinline__ void gload16(const void* g, void* l) {
    __builtin_amdgcn_global_load_lds((const AS1 unsigned int*)g, (AS3 unsigned int*)l, 16, 0, 0);
}

__device__ __forceinline__ unsigned short f2bf(float f) {
    union { float f; unsigned u; } x{f};
    unsigned r = x.u + 0x7FFFu + ((x.u >> 16) & 1u);
    return (unsigned short)(r >> 16);
}
__device__ __forceinline__ float bf2f(unsigned short u) {
    union { unsigned u; float f; } x; x.u = ((unsigned)u) << 16; return x.f;
}

// ---------- all 4 weight transposes in one launch ----------
__global__ __launch_bounds__(256) void k_transpose4(const float* W0, const float* W1,
                                                    const float* W2, const float* W3,
                                                    unsigned short* T0, unsigned short* T1,
                                                    unsigned short* T2, unsigned short* T3) {
    __shared__ float T[64][65];
    int sel = blockIdx.x >> 6, tile = blockIdx.x & 63;
    const float* W = sel == 0 ? W0 : sel == 1 ? W1 : sel == 2 ? W2 : W3;
    unsigned short* Wt = sel == 0 ? T0 : sel == 1 ? T1 : sel == 2 ? T2 : T3;
    int k0 = (tile >> 3) * 64, n0 = (tile & 7) * 64;
    int tid = threadIdx.x;
    for (int it = 0; it < 16; ++it) {
        int id = it * 256 + tid;
        int r = id >> 6, c = id & 63;
        T[r][c] = W[(k0 + r) * 512 + n0 + c];
    }
    __syncthreads();
    for (int it = 0; it < 16; ++it) {
        int id = it * 256 + tid;
        int r = id >> 6, c = id & 63;
        Wt[(n0 + r) * 512 + k0 + c] = f2bf(T[c][r]);
    }
}

// ---------- GEMM with f32 A operand: out[m][n] = bf16(A_f32[m][k]) * Wt[n][k]^T + bias ----------
// MODE 0: bf16 out scaled. MODE 1: bf16 VpT[b][d][key].
template <int MODE>
__global__ __launch_bounds__(256) void k_gemmF(const float* __restrict__ A,
                                               const unsigned short* __restrict__ Bt,
                                               const float* __restrict__ bias,
                                               void* __restrict__ outp,
                                               float scale) {
    __shared__ __align__(16) float AbS[2][4096];           // 2 x 128 x 32 f32
    __shared__ __align__(16) unsigned short BbS[2][4096];  // 2 x 128 x 32 bf16
    const int tid = threadIdx.x;
    const int lane = tid & 63, w = tid >> 6;
    int ib = blockIdx.x;
    const int mt = (ib & 7) | ((ib >> 5) << 3), nt = (ib >> 3) & 3;  // XCD swizzle
    const int m0 = mt * 128, n0 = nt * 128;
    const int wm = (w >> 1) * 64, wn = (w & 1) * 64;
    const int l15 = lane & 15, l4 = lane >> 4;

    const f32x4 vz = {0.f, 0.f, 0.f, 0.f};
    f32x4 acc[4][4];
    for (int i = 0; i < 4; ++i)
        for (int j = 0; j < 4; ++j) acc[i][j] = vz;

    const float* Abase = A + (size_t)m0 * 512;
    const unsigned short* Bbase = Bt + (size_t)n0 * 512;

    auto STAGE = [&](int ks, int p) {
        int kk = ks * 32;
        #pragma unroll
        for (int it = 0; it < 4; ++it) {
            int id = it * 256 + tid;
            int r = id >> 3, cc = id & 7, g = cc ^ (r & 7);
            gload16(Abase + r * 512 + kk + g * 4, &AbS[p][(it * 256 + w * 64) * 4]);
        }
        #pragma unroll
        for (int it = 0; it < 2; ++it) {
            int id = it * 256 + tid;
            int r = id >> 2, x = id & 3, c = x ^ (r & 3);
            gload16(Bbase + r * 512 + kk + c * 8, &BbS[p][(it * 256 + w * 64) * 8]);
        }
    };

    STAGE(0, 0);
    __syncthreads();
    for (int ks = 0; ks < 16; ++ks) {
        int p = ks & 1;
        if (ks < 15) STAGE(ks + 1, p ^ 1);
        bf16x8 af[4], bfr[4];
        #pragma unroll
        for (int i = 0; i < 4; ++i) {
            int r = wm + i * 16 + l15;
            int pc0 = (2 * l4) ^ (r & 7);
            const float* Af = &AbS[p][r * 32];
            f32x4 a0 = *(const f32x4*)(Af + pc0 * 4);
            f32x4 a1 = *(const f32x4*)(Af + (pc0 ^ 1) * 4);
            af[i] = bf16x8{(__bf16)a0[0], (__bf16)a0[1], (__bf16)a0[2], (__bf16)a0[3],
                           (__bf16)a1[0], (__bf16)a1[1], (__bf16)a1[2], (__bf16)a1[3]};
        }
        #pragma unroll
        for (int j = 0; j < 4; ++j) {
            int r = wn + j * 16 + l15, pc = l4 ^ (r & 3);
            bfr[j] = *(const bf16x8*)&BbS[p][r * 32 + pc * 8];
        }
        __builtin_amdgcn_s_setprio(1);
        #pragma unroll
        for (int i = 0; i < 4; ++i)
            #pragma unroll
            for (int j = 0; j < 4; ++j)
                acc[i][j] = MFMA(af[i], bfr[j], acc[i][j]);
        __builtin_amdgcn_s_setprio(0);
        __syncthreads();
    }

    float bn[4];
    for (int j = 0; j < 4; ++j) bn[j] = bias[n0 + wn + j * 16 + l15];

    if constexpr (MODE == 0) {
        unsigned short* out = (unsigned short*)outp;
        for (int i = 0; i < 4; ++i)
            for (int j = 0; j < 4; ++j)
                for (int rg = 0; rg < 4; ++rg) {
                    int m = m0 + wm + i * 16 + l4 * 4 + rg;
                    int n = n0 + wn + j * 16 + l15;
                    out[(size_t)m * 512 + n] = f2bf((acc[i][j][rg] + bn[j]) * scale);
                }
    } else {
        // MODE 1: VpT[b][d][key] via per-wave LDS transpose (reuse A staging region)
        unsigned short* T = (unsigned short*)&AbS[0][0] + w * 4096;
        __syncthreads();
        for (int i = 0; i < 4; ++i)
            for (int j = 0; j < 4; ++j)
                for (int rg = 0; rg < 4; ++rg) {
                    int ml = i * 16 + l4 * 4 + rg;   // key-local
                    int nl = j * 16 + l15;           // d-local
                    int pc = (ml >> 3) ^ (nl & 7);
                    T[nl * 64 + pc * 8 + (ml & 7)] = f2bf(acc[i][j][rg] + bn[j]);
                }
        unsigned short* out = (unsigned short*)outp;
        int b = (m0 + wm) >> 10;
        int key0 = (m0 + wm) & 1023;
        for (int it = 0; it < 8; ++it) {
            int ch = it * 64 + lane;
            int nl = ch >> 3, c = ch & 7, pc = c ^ (nl & 7);
            int4 v = *(const int4*)&T[nl * 64 + pc * 8];
            int d = n0 + wn + nl;
            *(int4*)(out + ((size_t)b * 512 + d) * 1024 + key0 + c * 8) = v;
        }
    }
}

// ---------- flash attention, 32x32 MFMA, 32 q/wave, no-max exp2 softmax ----------
// Qs pre-scaled by log2(e)/sqrt(512); O1b = bf16(Qs*invscale + softmax2(Qs K^T) V)
__global__ __launch_bounds__(256) void k_attn32(const unsigned short* __restrict__ Qs,
                                                const unsigned short* __restrict__ Kp,
                                                const unsigned short* __restrict__ VpT,
                                                unsigned short* __restrict__ O1b) {
    // u16 layout: K dbuf [0,8192) | V dbuf [8192,16384) | P 4 x (32 x 72) [16384,25600)
    __shared__ __align__(16) unsigned short sm[25600];
    const int tid = threadIdx.x, lane = tid & 63, w = tid >> 6;
    const int l31 = lane & 31, hi = lane >> 5;
    int i = blockIdx.x;
    const int xcd = i & 7, jj = i >> 3;
    const int qt = jj & 7, bhl = jj >> 3;
    const int bh = xcd * 16 + bhl;          // same (b,h) stays on one XCD
    const int h = bh & 7, b = bh >> 3;
    const int qrow = b * 1024 + qt * 128 + w * 32 + l31;

    const unsigned short* Ksrc = Kp + (size_t)(b * 1024) * 512 + h * 64;
    const unsigned short* Vsrc = VpT + (size_t)(b * 512 + h * 64) * 1024;
    const unsigned short* qptr = Qs + (size_t)qrow * 512 + h * 64;

    bf16x8 qf[4];
    #pragma unroll
    for (int ks = 0; ks < 4; ++ks)
        qf[ks] = *(const bf16x8*)(qptr + ks * 16 + hi * 8);

    f32x16 acc0, acc1;
    #pragma unroll
    for (int r = 0; r < 16; ++r) { acc0[r] = 0.f; acc1[r] = 0.f; }
    float ls = 0.f;

    unsigned short* Pw = sm + 16384 + w * 2304;   // [32 q][72 pad] bf16

    auto STAGE = [&](int kv, int p) {
        #pragma unroll
        for (int it = 0; it < 2; ++it) {
            int id = it * 256 + tid;
            int r = id >> 3, x = id & 7, c = x ^ (r & 7);
            unsigned short* ldsb = sm + p * 4096 + (it * 256 + w * 64) * 8;
            gload16(Ksrc + (size_t)(kv * 64 + r) * 512 + c * 8, ldsb);
            gload16(Vsrc + (size_t)r * 1024 + kv * 64 + c * 8, ldsb + 8192);
        }
    };

    STAGE(0, 0);
    __syncthreads();
    for (int kv = 0; kv < 16; ++kv) {
        int p = kv & 1;
        if (kv < 15) STAGE(kv + 1, p ^ 1);
        const unsigned short* Kl = sm + p * 4096;
        const unsigned short* Vl = sm + 8192 + p * 4096;
        const int rsw = (l31 & 7);   // row-swizzle term (same for rows l31 and 32+l31)

        // S^T[key][q] = mfma32(K, Q): lane owns q=l31; regs+hi give 32 keys per tile
        f32x16 s0, s1;
        #pragma unroll
        for (int r = 0; r < 16; ++r) { s0[r] = 0.f; s1[r] = 0.f; }
        __builtin_amdgcn_s_setprio(1);
        #pragma unroll
        for (int ks = 0; ks < 4; ++ks) {
            int c = (2 * ks + hi) ^ rsw;
            bf16x8 kf0 = *(const bf16x8*)&Kl[l31 * 64 + c * 8];
            s0 = MFMA32(kf0, qf[ks], s0);
            bf16x8 kf1 = *(const bf16x8*)&Kl[(32 + l31) * 64 + c * 8];
            s1 = MFMA32(kf1, qf[ks], s1);
        }
        __builtin_amdgcn_s_setprio(0);

        // p = 2^s, deferred row-sum, pack to per-wave P LDS
        #pragma unroll
        for (int g = 0; g < 4; ++g) {
            float e0 = __builtin_amdgcn_exp2f(s0[4 * g + 0]);
            float e1 = __builtin_amdgcn_exp2f(s0[4 * g + 1]);
            float e2 = __builtin_amdgcn_exp2f(s0[4 * g + 2]);
            float e3 = __builtin_amdgcn_exp2f(s0[4 * g + 3]);
            float f0 = __builtin_amdgcn_exp2f(s1[4 * g + 0]);
            float f1 = __builtin_amdgcn_exp2f(s1[4 * g + 1]);
            float f2 = __builtin_amdgcn_exp2f(s1[4 * g + 2]);
            float f3 = __builtin_amdgcn_exp2f(s1[4 * g + 3]);
            ls += ((e0 + e1) + (e2 + e3)) + ((f0 + f1) + (f2 + f3));
            bf16x4 pv0 = {(__bf16)e0, (__bf16)e1, (__bf16)e2, (__bf16)e3};
            bf16x4 pv1 = {(__bf16)f0, (__bf16)f1, (__bf16)f2, (__bf16)f3};
            *(bf16x4*)&Pw[l31 * 72 + 8 * g + 4 * hi] = pv0;        // keys 8g+4hi+0..3
            *(bf16x4*)&Pw[l31 * 72 + 32 + 8 * g + 4 * hi] = pv1;   // keys 32+...
        }

        // PV: O^T[d][q] = mfma32(V^T, P^T)
        bf16x8 pf[4];
        #pragma unroll
        for (int ks = 0; ks < 4; ++ks)
            pf[ks] = *(const bf16x8*)&Pw[l31 * 72 + ks * 16 + hi * 8];
        __builtin_amdgcn_s_setprio(1);
        #pragma unroll
        for (int ks = 0; ks < 4; ++ks) {
            int c = (2 * ks + hi) ^ rsw;
            bf16x8 vf0 = *(const bf16x8*)&Vl[l31 * 64 + c * 8];
            acc0 = MFMA32(vf0, pf[ks], acc0);
            bf16x8 vf1 = *(const bf16x8*)&Vl[(32 + l31) * 64 + c * 8];
            acc1 = MFMA32(vf1, pf[ks], acc1);
        }
        __builtin_amdgcn_s_setprio(0);
        __syncthreads();
    }

    ls += __shfl_xor(ls, 32);
    float linv = 1.0f / ls;
    const float invscale = 15.6841306f;  // sqrt(512)/log2(e)
    unsigned short* orow = O1b + (size_t)qrow * 512 + h * 64;
    #pragma unroll
    for (int g = 0; g < 4; ++g) {
        {   // dt = 0
            int d0 = 8 * g + 4 * hi;
            bf16x4 qres = *(const bf16x4*)(qptr + d0);
            bf16x4 ov;
            ov[0] = (__bf16)((float)qres[0] * invscale + acc0[4 * g + 0] * linv);
            ov[1] = (__bf16)((float)qres[1] * invscale + acc0[4 * g + 1] * linv);
            ov[2] = (__bf16)((float)qres[2] * invscale + acc0[4 * g + 2] * linv);
            ov[3] = (__bf16)((float)qres[3] * invscale + acc0[4 * g + 3] * linv);
            *(bf16x4*)(orow + d0) = ov;
        }
        {   // dt = 1
            int d0 = 32 + 8 * g + 4 * hi;
            bf16x4 qres = *(const bf16x4*)(qptr + d0);
            bf16x4 ov;
            ov[0] = (__bf16)((float)qres[0] * invscale + acc1[4 * g + 0] * linv);
            ov[1] = (__bf16)((float)qres[1] * invscale + acc1[4 * g + 1] * linv);
            ov[2] = (__bf16)((float)qres[2] * invscale + acc1[4 * g + 2] * linv);
            ov[3] = (__bf16)((float)qres[3] * invscale + acc1[4 * g + 3] * linv);
            *(bf16x4*)(orow + d0) = ov;
        }
    }
}

// ---------- LayerNorm bf16 in -> bf16 out ----------
__global__ __launch_bounds__(256) void k_ln_bf(const unsigned short* __restrict__ in,
                                               unsigned short* __restrict__ outb,
                                               const float* __restrict__ g,
                                               const float* __restrict__ bt) {
    int row = blockIdx.x * 4 + (threadIdx.x >> 6);
    int lane = threadIdx.x & 63;
    const unsigned short* x = in + (size_t)row * 512 + lane * 8;
    bf16x8 v = *(const bf16x8*)x;
    float f[8];
    for (int j = 0; j < 8; ++j) f[j] = (float)v[j];
    float s1 = 0.f, s2 = 0.f;
    for (int j = 0; j < 8; ++j) { s1 += f[j]; s2 += f[j] * f[j]; }
    for (int off = 32; off; off >>= 1) {
        s1 += __shfl_xor(s1, off);
        s2 += __shfl_xor(s2, off);
    }
    float mu = s1 * (1.f / 512.f);
    float var = s2 * (1.f / 512.f) - mu * mu;
    float rs = rsqrtf(var + 1e-5f);
    float4 ga = *(const float4*)(g + lane * 8), gb = *(const float4*)(g + lane * 8 + 4);
    float4 ba = *(const float4*)(bt + lane * 8), bb = *(const float4*)(bt + lane * 8 + 4);
    float gg[8] = {ga.x, ga.y, ga.z, ga.w, gb.x, gb.y, gb.z, gb.w};
    float bv[8] = {ba.x, ba.y, ba.z, ba.w, bb.x, bb.y, bb.z, bb.w};
    bf16x8 y;
    for (int j = 0; j < 8; ++j) y[j] = (__bf16)((f[j] - mu) * rs * gg[j] + bv[j]);
    *(bf16x8*)(outb + (size_t)row * 512 + lane * 8) = y;
}

// ---------- fused FFN GEMM + residual + final LayerNorm ----------
__global__ __launch_bounds__(512, 2) void k_gemm2ln(const unsigned short* __restrict__ A,
                                                    const unsigned short* __restrict__ Bt,
                                                    const float* __restrict__ bias,
                                                    const float* __restrict__ g1,
                                                    const float* __restrict__ b1,
                                                    float* __restrict__ out) {
    __shared__ __align__(16) unsigned short Ab[2][2048];    // 64 x 32
    __shared__ __align__(16) unsigned short Bb[2][16384];   // 512 x 32
    __shared__ float part[64][4][2];
    __shared__ float stats[64][2];
    const int tid = threadIdx.x, lane = tid & 63, w = tid >> 6;
    const int l15 = lane & 15, l4 = lane >> 4;
    const int m0 = blockIdx.x * 64;
    const int wm = (w >> 2) * 32, wn = (w & 3) * 128;

    const f32x4 vz = {0.f, 0.f, 0.f, 0.f};
    f32x4 acc[2][8];
    for (int i = 0; i < 2; ++i)
        for (int j = 0; j < 8; ++j) acc[i][j] = vz;

    const unsigned short* Abase = A + (size_t)m0 * 512;

    auto STAGE = [&](int ks, int p) {
        int kk = ks * 32;
        for (int it = 0; it < 4; ++it) {
            int id = it * 512 + tid;
            int r = id >> 2, x = id & 3, c = x ^ (r & 3);
            gload16(Bt + r * 512 + kk + c * 8, &Bb[p][(it * 512 + w * 64) * 8]);
        }
        if (w < 4) {
            int id = w * 64 + lane;
            int r = id >> 2, x = id & 3, c = x ^ (r & 3);
            gload16(Abase + r * 512 + kk + c * 8, &Ab[p][(w * 64) * 8]);
        }
    };

    STAGE(0, 0);
    __syncthreads();
    for (int ks = 0; ks < 16; ++ks) {
        int p = ks & 1;
        if (ks < 15) STAGE(ks + 1, p ^ 1);
        bf16x8 af[2], bfr[8];
        for (int i = 0; i < 2; ++i) {
            int r = wm + i * 16 + l15, pc = l4 ^ (r & 3);
            af[i] = *(const bf16x8*)&Ab[p][r * 32 + pc * 8];
        }
        for (int j = 0; j < 8; ++j) {
            int r = wn + j * 16 + l15, pc = l4 ^ (r & 3);
            bfr[j] = *(const bf16x8*)&Bb[p][r * 32 + pc * 8];
        }
        __builtin_amdgcn_s_setprio(1);
        for (int i = 0; i < 2; ++i)
            for (int j = 0; j < 8; ++j)
                acc[i][j] = MFMA(af[i], bfr[j], acc[i][j]);
        __builtin_amdgcn_s_setprio(0);
        __syncthreads();
    }

    float bn[8], gv[8], bv2[8];
    for (int j = 0; j < 8; ++j) {
        int n = wn + j * 16 + l15;
        bn[j] = bias[n]; gv[j] = g1[n]; bv2[j] = b1[n];
    }
    f32x4 s1v[2], s2v[2];
    for (int i = 0; i < 2; ++i) { s1v[i] = vz; s2v[i] = vz; }
    for (int i = 0; i < 2; ++i)
        for (int j = 0; j < 8; ++j)
            for (int rg = 0; rg < 4; ++rg) {
                int row = m0 + wm + i * 16 + l4 * 4 + rg;
                int n = wn + j * 16 + l15;
                float z = acc[i][j][rg] + bn[j];
                z = z > 0.f ? z : 0.f;
                float v = bf2f(A[(size_t)row * 512 + n]) + z;
                acc[i][j][rg] = v;
                s1v[i][rg] += v;
                s2v[i][rg] += v * v;
            }
    for (int i = 0; i < 2; ++i)
        for (int rg = 0; rg < 4; ++rg) {
            float a = s1v[i][rg], c = s2v[i][rg];
            for (int off = 1; off < 16; off <<= 1) {
                a += __shfl_xor(a, off);
                c += __shfl_xor(c, off);
            }
            s1v[i][rg] = a; s2v[i][rg] = c;
        }
    if (l15 == 0)
        for (int i = 0; i < 2; ++i)
            for (int rg = 0; rg < 4; ++rg) {
                int rl = wm + i * 16 + l4 * 4 + rg;
                part[rl][w & 3][0] = s1v[i][rg];
                part[rl][w & 3][1] = s2v[i][rg];
            }
    __syncthreads();
    if (tid < 64) {
        float a = 0.f, c = 0.f;
        for (int q = 0; q < 4; ++q) { a += part[tid][q][0]; c += part[tid][q][1]; }
        float mu = a * (1.f / 512.f);
        float var = c * (1.f / 512.f) - mu * mu;
        stats[tid][0] = mu;
        stats[tid][1] = rsqrtf(var + 1e-5f);
    }
    __syncthreads();
    for (int i = 0; i < 2; ++i)
        for (int rg = 0; rg < 4; ++rg) {
            int rl = wm + i * 16 + l4 * 4 + rg;
            float mu = stats[rl][0], rs = stats[rl][1];
            for (int j = 0; j < 8; ++j) {
                int n = wn + j * 16 + l15;
                out[(size_t)(m0 + rl) * 512 + n] = (acc[i][j][rg] - mu) * rs * gv[j] + bv2[j];
            }
        }
}

extern "C" void kernel_launch(void* const* d_in, const int* in_sizes, int n_in,
                              void* d_out, int out_size, void* d_ws, size_t ws_size,
                              hipStream_t stream) {
    const float* Q  = (const float*)d_in[0];
    const float* K  = (const float*)d_in[1];
    const float* Wq = (const float*)d_in[2];
    const float* bq = (const float*)d_in[3];
    const float* Wk = (const float*)d_in[4];
    const float* bk = (const float*)d_in[5];
    const float* Wv = (const float*)d_in[6];
    const float* bv = (const float*)d_in[7];
    const float* Wo = (const float*)d_in[8];
    const float* bo = (const float*)d_in[9];
    const float* g0 = (const float*)d_in[10];
    const float* b0 = (const float*)d_in[11];
    const float* g1 = (const float*)d_in[12];
    const float* b1 = (const float*)d_in[13];
    float* out = (float*)d_out;

    const size_t SZ_BF = (size_t)16384 * 512 * 2;
    const size_t SZ_W  = (size_t)512 * 512 * 2;
    char* p = (char*)d_ws;
    unsigned short* Wqt = (unsigned short*)p; p += SZ_W;
    unsigned short* Wkt = (unsigned short*)p; p += SZ_W;
    unsigned short* Wvt = (unsigned short*)p; p += SZ_W;
    unsigned short* Wot = (unsigned short*)p; p += SZ_W;
    unsigned short* Qsc = (unsigned short*)p; p += SZ_BF;   // Q proj, pre-scaled log2e/sqrt(512)
    unsigned short* Kp  = (unsigned short*)p; p += SZ_BF;
    unsigned short* VpT = (unsigned short*)p; p += SZ_BF;
    unsigned short* A1b = (unsigned short*)p; p += SZ_BF;   // attn out (pre-LN0)
    unsigned short* X0b = (unsigned short*)p; p += SZ_BF;   // LN0 out

    k_transpose4<<<256, 256, 0, stream>>>(Wq, Wk, Wv, Wo, Wqt, Wkt, Wvt, Wot);

    const float scale2 = 0.063758718f;  // log2(e)/sqrt(512)
    k_gemmF<0><<<512, 256, 0, stream>>>(Q, Wqt, bq, Qsc, scale2);
    k_gemmF<0><<<512, 256, 0, stream>>>(K, Wkt, bk, Kp, 1.0f);
    k_gemmF<1><<<512, 256, 0, stream>>>(K, Wvt, bv, VpT, 1.0f);

    k_attn32<<<1024, 256, 0, stream>>>(Qsc, Kp, VpT, A1b);

    k_ln_bf<<<4096, 256, 0, stream>>>(A1b, X0b, g0, b0);
    k_gemm2ln<<<256, 512, 0, stream>>>(X0b, Wot, bo, g1, b1, out);
}

// Round 6
// 154.645 us; speedup vs baseline: 1.0013x; 1.0013x over previous
//
#include <hip/hip_runtime.h>
#include <hip/hip_bf16.h>

typedef float f32x4 __attribute__((ext_vector_type(4)));
typedef float f32x16 __attribute__((ext_vector_type(16)));
typedef __bf16 bf16x8 __attribute__((ext_vector_type(8)));
typedef __bf16 bf16x4 __attribute__((ext_vector_type(4)));

#define MFMA(a, b, c) __builtin_amdgcn_mfma_f32_16x16x32_bf16(a, b, c, 0, 0, 0)
#define MFMA32(a, b, c) __builtin_amdgcn_mfma_f32_32x32x16_bf16(a, b, c, 0, 0, 0)
#define AS1 __attribute__((address_space(1)))
#define AS3 __attribute__((address_space(3)))

__device__ __forceinline__ void gload16(const void* g, void* l) {
    __builtin_amdgcn_global_load_lds((const AS1 unsigned int*)g, (AS3 unsigned int*)l, 16, 0, 0);
}

__device__ __forceinline__ unsigned short f2bf(float f) {
    union { float f; unsigned u; } x{f};
    unsigned r = x.u + 0x7FFFu + ((x.u >> 16) & 1u);
    return (unsigned short)(r >> 16);
}
__device__ __forceinline__ float bf2f(unsigned short u) {
    union { unsigned u; float f; } x; x.u = ((unsigned)u) << 16; return x.f;
}
__device__ __forceinline__ unsigned pkbf(float a, float b) {
    union { __bf16 h[2]; unsigned u; } r;
    r.h[0] = (__bf16)a; r.h[1] = (__bf16)b;
    return r.u;
}

// ---------- all 4 weight transposes in one launch ----------
__global__ __launch_bounds__(256) void k_transpose4(const float* W0, const float* W1,
                                                    const float* W2, const float* W3,
                                                    unsigned short* T0, unsigned short* T1,
                                                    unsigned short* T2, unsigned short* T3) {
    __shared__ float T[64][65];
    int sel = blockIdx.x >> 6, tile = blockIdx.x & 63;
    const float* W = sel == 0 ? W0 : sel == 1 ? W1 : sel == 2 ? W2 : W3;
    unsigned short* Wt = sel == 0 ? T0 : sel == 1 ? T1 : sel == 2 ? T2 : T3;
    int k0 = (tile >> 3) * 64, n0 = (tile & 7) * 64;
    int tid = threadIdx.x;
    for (int it = 0; it < 16; ++it) {
        int id = it * 256 + tid;
        int r = id >> 6, c = id & 63;
        T[r][c] = W[(k0 + r) * 512 + n0 + c];
    }
    __syncthreads();
    for (int it = 0; it < 16; ++it) {
        int id = it * 256 + tid;
        int r = id >> 6, c = id & 63;
        Wt[(n0 + r) * 512 + k0 + c] = f2bf(T[c][r]);
    }
}

// ---------- GEMM with f32 A operand: out[m][n] = bf16(A_f32[m][k]) * Wt[n][k]^T + bias ----------
// MODE 0: bf16 out scaled. MODE 1: bf16 VpT[b][d][key].
template <int MODE>
__global__ __launch_bounds__(256) void k_gemmF(const float* __restrict__ A,
                                               const unsigned short* __restrict__ Bt,
                                               const float* __restrict__ bias,
                                               void* __restrict__ outp,
                                               float scale) {
    __shared__ __align__(16) float AbS[2][4096];           // 2 x 128 x 32 f32
    __shared__ __align__(16) unsigned short BbS[2][4096];  // 2 x 128 x 32 bf16
    const int tid = threadIdx.x;
    const int lane = tid & 63, w = tid >> 6;
    int ib = blockIdx.x;
    const int mt = (ib & 7) | ((ib >> 5) << 3), nt = (ib >> 3) & 3;  // XCD swizzle
    const int m0 = mt * 128, n0 = nt * 128;
    const int wm = (w >> 1) * 64, wn = (w & 1) * 64;
    const int l15 = lane & 15, l4 = lane >> 4;

    const f32x4 vz = {0.f, 0.f, 0.f, 0.f};
    f32x4 acc[4][4];
    for (int i = 0; i < 4; ++i)
        for (int j = 0; j < 4; ++j) acc[i][j] = vz;

    const float* Abase = A + (size_t)m0 * 512;
    const unsigned short* Bbase = Bt + (size_t)n0 * 512;

    auto STAGE = [&](int ks, int p) {
        int kk = ks * 32;
        #pragma unroll
        for (int it = 0; it < 4; ++it) {
            int id = it * 256 + tid;
            int r = id >> 3, cc = id & 7, g = cc ^ (r & 7);
            gload16(Abase + r * 512 + kk + g * 4, &AbS[p][(it * 256 + w * 64) * 4]);
        }
        #pragma unroll
        for (int it = 0; it < 2; ++it) {
            int id = it * 256 + tid;
            int r = id >> 2, x = id & 3, c = x ^ (r & 3);
            gload16(Bbase + r * 512 + kk + c * 8, &BbS[p][(it * 256 + w * 64) * 8]);
        }
    };

    STAGE(0, 0);
    __syncthreads();
    for (int ks = 0; ks < 16; ++ks) {
        int p = ks & 1;
        if (ks < 15) STAGE(ks + 1, p ^ 1);
        bf16x8 af[4], bfr[4];
        #pragma unroll
        for (int i = 0; i < 4; ++i) {
            int r = wm + i * 16 + l15;
            int pc0 = (2 * l4) ^ (r & 7);
            const float* Af = &AbS[p][r * 32];
            f32x4 a0 = *(const f32x4*)(Af + pc0 * 4);
            f32x4 a1 = *(const f32x4*)(Af + (pc0 ^ 1) * 4);
            af[i] = bf16x8{(__bf16)a0[0], (__bf16)a0[1], (__bf16)a0[2], (__bf16)a0[3],
                           (__bf16)a1[0], (__bf16)a1[1], (__bf16)a1[2], (__bf16)a1[3]};
        }
        #pragma unroll
        for (int j = 0; j < 4; ++j) {
            int r = wn + j * 16 + l15, pc = l4 ^ (r & 3);
            bfr[j] = *(const bf16x8*)&BbS[p][r * 32 + pc * 8];
        }
        __builtin_amdgcn_s_setprio(1);
        #pragma unroll
        for (int i = 0; i < 4; ++i)
            #pragma unroll
            for (int j = 0; j < 4; ++j)
                acc[i][j] = MFMA(af[i], bfr[j], acc[i][j]);
        __builtin_amdgcn_s_setprio(0);
        __syncthreads();
    }

    float bn[4];
    for (int j = 0; j < 4; ++j) bn[j] = bias[n0 + wn + j * 16 + l15];

    if constexpr (MODE == 0) {
        unsigned short* out = (unsigned short*)outp;
        for (int i = 0; i < 4; ++i)
            for (int j = 0; j < 4; ++j)
                for (int rg = 0; rg < 4; ++rg) {
                    int m = m0 + wm + i * 16 + l4 * 4 + rg;
                    int n = n0 + wn + j * 16 + l15;
                    out[(size_t)m * 512 + n] = f2bf((acc[i][j][rg] + bn[j]) * scale);
                }
    } else {
        // MODE 1: VpT[b][d][key] via per-wave LDS transpose (reuse A staging region)
        unsigned short* T = (unsigned short*)&AbS[0][0] + w * 4096;
        __syncthreads();
        for (int i = 0; i < 4; ++i)
            for (int j = 0; j < 4; ++j)
                for (int rg = 0; rg < 4; ++rg) {
                    int ml = i * 16 + l4 * 4 + rg;   // key-local
                    int nl = j * 16 + l15;           // d-local
                    int pc = (ml >> 3) ^ (nl & 7);
                    T[nl * 64 + pc * 8 + (ml & 7)] = f2bf(acc[i][j][rg] + bn[j]);
                }
        unsigned short* out = (unsigned short*)outp;
        int b = (m0 + wm) >> 10;
        int key0 = (m0 + wm) & 1023;
        for (int it = 0; it < 8; ++it) {
            int ch = it * 64 + lane;
            int nl = ch >> 3, c = ch & 7, pc = c ^ (nl & 7);
            int4 v = *(const int4*)&T[nl * 64 + pc * 8];
            int d = n0 + wn + nl;
            *(int4*)(out + ((size_t)b * 512 + d) * 1024 + key0 + c * 8) = v;
        }
    }
}

// ---------- flash attention, 32x32 MFMA, P kept in registers via shfl_xor(32) ----------
// Qs pre-scaled by log2(e)/sqrt(512); O1b = bf16(Qs*invscale + softmax2(Qs K^T) V)
__global__ __launch_bounds__(256, 4) void k_attn32(const unsigned short* __restrict__ Qs,
                                                   const unsigned short* __restrict__ Kp,
                                                   const unsigned short* __restrict__ VpT,
                                                   unsigned short* __restrict__ O1b) {
    // u16 layout: K dbuf [0,8192) | V dbuf [8192,16384)
    __shared__ __align__(16) unsigned short sm[16384];
    const int tid = threadIdx.x, lane = tid & 63, w = tid >> 6;
    const int l31 = lane & 31, hi = lane >> 5;
    int i = blockIdx.x;
    const int xcd = i & 7, jj = i >> 3;
    const int qt = jj & 7, bhl = jj >> 3;
    const int bh = xcd * 16 + bhl;          // same (b,h) stays on one XCD
    const int h = bh & 7, b = bh >> 3;
    const int qrow = b * 1024 + qt * 128 + w * 32 + l31;

    const unsigned short* Ksrc = Kp + (size_t)(b * 1024) * 512 + h * 64;
    const unsigned short* Vsrc = VpT + (size_t)(b * 512 + h * 64) * 1024;
    const unsigned short* qptr = Qs + (size_t)qrow * 512 + h * 64;

    bf16x8 qf[4];
    #pragma unroll
    for (int ks = 0; ks < 4; ++ks)
        qf[ks] = *(const bf16x8*)(qptr + ks * 16 + hi * 8);

    f32x16 acc0, acc1;
    #pragma unroll
    for (int r = 0; r < 16; ++r) { acc0[r] = 0.f; acc1[r] = 0.f; }
    float ls = 0.f;

    auto STAGE = [&](int kv, int p) {
        #pragma unroll
        for (int it = 0; it < 2; ++it) {
            int id = it * 256 + tid;
            int r = id >> 3, x = id & 7, c = x ^ (r & 7);
            unsigned short* ldsb = sm + p * 4096 + (it * 256 + w * 64) * 8;
            gload16(Ksrc + (size_t)(kv * 64 + r) * 512 + c * 8, ldsb);
            gload16(Vsrc + (size_t)r * 1024 + kv * 64 + c * 8, ldsb + 8192);
        }
    };

    STAGE(0, 0);
    __syncthreads();
    for (int kv = 0; kv < 16; ++kv) {
        int p = kv & 1;
        if (kv < 15) STAGE(kv + 1, p ^ 1);
        const unsigned short* Kl = sm + p * 4096;
        const unsigned short* Vl = sm + 8192 + p * 4096;
        const int rsw = (l31 & 7);   // row-swizzle term (rows l31 and 32+l31 share it)

        // S^T[key][q] = mfma32(K, Q): lane owns q=l31; s0 = keys 0..31, s1 = keys 32..63
        f32x16 s0, s1;
        #pragma unroll
        for (int r = 0; r < 16; ++r) { s0[r] = 0.f; s1[r] = 0.f; }
        __builtin_amdgcn_s_setprio(1);
        #pragma unroll
        for (int ks = 0; ks < 4; ++ks) {
            int c = (2 * ks + hi) ^ rsw;
            bf16x8 kf0 = *(const bf16x8*)&Kl[l31 * 64 + c * 8];
            s0 = MFMA32(kf0, qf[ks], s0);
            bf16x8 kf1 = *(const bf16x8*)&Kl[(32 + l31) * 64 + c * 8];
            s1 = MFMA32(kf1, qf[ks], s1);
        }
        __builtin_amdgcn_s_setprio(0);

        // p = 2^s; pack to bf16 words. s-reg 4g+j -> key 8g + 4*hi + j.
        // We[2g+t] = keys 8g+4hi+{2t,2t+1} (keys 0..31); Wf same for keys 32..63.
        unsigned We[8], Wf[8];
        #pragma unroll
        for (int g = 0; g < 4; ++g) {
            float e0 = __builtin_amdgcn_exp2f(s0[4 * g + 0]);
            float e1 = __builtin_amdgcn_exp2f(s0[4 * g + 1]);
            float e2 = __builtin_amdgcn_exp2f(s0[4 * g + 2]);
            float e3 = __builtin_amdgcn_exp2f(s0[4 * g + 3]);
            float f0 = __builtin_amdgcn_exp2f(s1[4 * g + 0]);
            float f1 = __builtin_amdgcn_exp2f(s1[4 * g + 1]);
            float f2 = __builtin_amdgcn_exp2f(s1[4 * g + 2]);
            float f3 = __builtin_amdgcn_exp2f(s1[4 * g + 3]);
            ls += ((e0 + e1) + (e2 + e3)) + ((f0 + f1) + (f2 + f3));
            We[2 * g + 0] = pkbf(e0, e1); We[2 * g + 1] = pkbf(e2, e3);
            Wf[2 * g + 0] = pkbf(f0, f1); Wf[2 * g + 1] = pkbf(f2, f3);
        }
        // Assemble PV B-frags in-register via shfl_xor(32) partner exchange.
        // frag[k2] needs w_t = keys 16*k2 + 8*hi + {2t,2t+1}:
        //   hi=0: w0,w1 = own A0,A1;            w2,w3 = partner A0,A1
        //   hi=1: w0,w1 = partner B0,B1;        w2,w3 = own B0,B1
        // where A_t = W[4k2+t] (low-g pair), B_t = W[4k2+2+t] (high-g pair).
        bf16x8 pf[4];
        #pragma unroll
        for (int src = 0; src < 2; ++src) {
            const unsigned* W = src == 0 ? We : Wf;
            #pragma unroll
            for (int k2 = 0; k2 < 2; ++k2) {
                unsigned A0 = W[4 * k2 + 0], A1 = W[4 * k2 + 1];
                unsigned B0 = W[4 * k2 + 2], B1 = W[4 * k2 + 3];
                unsigned cross0 = __shfl_xor(hi ? A0 : B0, 32);
                unsigned cross1 = __shfl_xor(hi ? A1 : B1, 32);
                union { unsigned w[4]; bf16x8 v; } r;
                r.w[0] = hi ? cross0 : A0;
                r.w[1] = hi ? cross1 : A1;
                r.w[2] = hi ? B0 : cross0;
                r.w[3] = hi ? B1 : cross1;
                pf[src * 2 + k2] = r.v;
            }
        }

        // PV: O^T[d][q] = mfma32(V^T, P^T)
        __builtin_amdgcn_s_setprio(1);
        #pragma unroll
        for (int ks = 0; ks < 4; ++ks) {
            int c = (2 * ks + hi) ^ rsw;
            bf16x8 vf0 = *(const bf16x8*)&Vl[l31 * 64 + c * 8];
            acc0 = MFMA32(vf0, pf[ks], acc0);
            bf16x8 vf1 = *(const bf16x8*)&Vl[(32 + l31) * 64 + c * 8];
            acc1 = MFMA32(vf1, pf[ks], acc1);
        }
        __builtin_amdgcn_s_setprio(0);
        __syncthreads();
    }

    ls += __shfl_xor(ls, 32);
    float linv = 1.0f / ls;
    const float invscale = 15.6841306f;  // sqrt(512)/log2(e)
    unsigned short* orow = O1b + (size_t)qrow * 512 + h * 64;
    #pragma unroll
    for (int g = 0; g < 4; ++g) {
        {   // dt = 0
            int d0 = 8 * g + 4 * hi;
            bf16x4 qres = *(const bf16x4*)(qptr + d0);
            bf16x4 ov;
            ov[0] = (__bf16)((float)qres[0] * invscale + acc0[4 * g + 0] * linv);
            ov[1] = (__bf16)((float)qres[1] * invscale + acc0[4 * g + 1] * linv);
            ov[2] = (__bf16)((float)qres[2] * invscale + acc0[4 * g + 2] * linv);
            ov[3] = (__bf16)((float)qres[3] * invscale + acc0[4 * g + 3] * linv);
            *(bf16x4*)(orow + d0) = ov;
        }
        {   // dt = 1
            int d0 = 32 + 8 * g + 4 * hi;
            bf16x4 qres = *(const bf16x4*)(qptr + d0);
            bf16x4 ov;
            ov[0] = (__bf16)((float)qres[0] * invscale + acc1[4 * g + 0] * linv);
            ov[1] = (__bf16)((float)qres[1] * invscale + acc1[4 * g + 1] * linv);
            ov[2] = (__bf16)((float)qres[2] * invscale + acc1[4 * g + 2] * linv);
            ov[3] = (__bf16)((float)qres[3] * invscale + acc1[4 * g + 3] * linv);
            *(bf16x4*)(orow + d0) = ov;
        }
    }
}

// ---------- LayerNorm bf16 in -> bf16 out ----------
__global__ __launch_bounds__(256) void k_ln_bf(const unsigned short* __restrict__ in,
                                               unsigned short* __restrict__ outb,
                                               const float* __restrict__ g,
                                               const float* __restrict__ bt) {
    int row = blockIdx.x * 4 + (threadIdx.x >> 6);
    int lane = threadIdx.x & 63;
    const unsigned short* x = in + (size_t)row * 512 + lane * 8;
    bf16x8 v = *(const bf16x8*)x;
    float f[8];
    for (int j = 0; j < 8; ++j) f[j] = (float)v[j];
    float s1 = 0.f, s2 = 0.f;
    for (int j = 0; j < 8; ++j) { s1 += f[j]; s2 += f[j] * f[j]; }
    for (int off = 32; off; off >>= 1) {
        s1 += __shfl_xor(s1, off);
        s2 += __shfl_xor(s2, off);
    }
    float mu = s1 * (1.f / 512.f);
    float var = s2 * (1.f / 512.f) - mu * mu;
    float rs = rsqrtf(var + 1e-5f);
    float4 ga = *(const float4*)(g + lane * 8), gb = *(const float4*)(g + lane * 8 + 4);
    float4 ba = *(const float4*)(bt + lane * 8), bb = *(const float4*)(bt + lane * 8 + 4);
    float gg[8] = {ga.x, ga.y, ga.z, ga.w, gb.x, gb.y, gb.z, gb.w};
    float bv[8] = {ba.x, ba.y, ba.z, ba.w, bb.x, bb.y, bb.z, bb.w};
    bf16x8 y;
    for (int j = 0; j < 8; ++j) y[j] = (__bf16)((f[j] - mu) * rs * gg[j] + bv[j]);
    *(bf16x8*)(outb + (size_t)row * 512 + lane * 8) = y;
}

// ---------- fused FFN GEMM + residual + final LayerNorm ----------
__global__ __launch_bounds__(512, 2) void k_gemm2ln(const unsigned short* __restrict__ A,
                                                    const unsigned short* __restrict__ Bt,
                                                    const float* __restrict__ bias,
                                                    const float* __restrict__ g1,
                                                    const float* __restrict__ b1,
                                                    float* __restrict__ out) {
    __shared__ __align__(16) unsigned short Ab[2][2048];    // 64 x 32
    __shared__ __align__(16) unsigned short Bb[2][16384];   // 512 x 32
    __shared__ float part[64][4][2];
    __shared__ float stats[64][2];
    const int tid = threadIdx.x, lane = tid & 63, w = tid >> 6;
    const int l15 = lane & 15, l4 = lane >> 4;
    const int m0 = blockIdx.x * 64;
    const int wm = (w >> 2) * 32, wn = (w & 3) * 128;

    const f32x4 vz = {0.f, 0.f, 0.f, 0.f};
    f32x4 acc[2][8];
    for (int i = 0; i < 2; ++i)
        for (int j = 0; j < 8; ++j) acc[i][j] = vz;

    const unsigned short* Abase = A + (size_t)m0 * 512;

    auto STAGE = [&](int ks, int p) {
        int kk = ks * 32;
        for (int it = 0; it < 4; ++it) {
            int id = it * 512 + tid;
            int r = id >> 2, x = id & 3, c = x ^ (r & 3);
            gload16(Bt + r * 512 + kk + c * 8, &Bb[p][(it * 512 + w * 64) * 8]);
        }
        if (w < 4) {
            int id = w * 64 + lane;
            int r = id >> 2, x = id & 3, c = x ^ (r & 3);
            gload16(Abase + r * 512 + kk + c * 8, &Ab[p][(w * 64) * 8]);
        }
    };

    STAGE(0, 0);
    __syncthreads();
    for (int ks = 0; ks < 16; ++ks) {
        int p = ks & 1;
        if (ks < 15) STAGE(ks + 1, p ^ 1);
        bf16x8 af[2], bfr[8];
        for (int i = 0; i < 2; ++i) {
            int r = wm + i * 16 + l15, pc = l4 ^ (r & 3);
            af[i] = *(const bf16x8*)&Ab[p][r * 32 + pc * 8];
        }
        for (int j = 0; j < 8; ++j) {
            int r = wn + j * 16 + l15, pc = l4 ^ (r & 3);
            bfr[j] = *(const bf16x8*)&Bb[p][r * 32 + pc * 8];
        }
        __builtin_amdgcn_s_setprio(1);
        for (int i = 0; i < 2; ++i)
            for (int j = 0; j < 8; ++j)
                acc[i][j] = MFMA(af[i], bfr[j], acc[i][j]);
        __builtin_amdgcn_s_setprio(0);
        __syncthreads();
    }

    float bn[8], gv[8], bv2[8];
    for (int j = 0; j < 8; ++j) {
        int n = wn + j * 16 + l15;
        bn[j] = bias[n]; gv[j] = g1[n]; bv2[j] = b1[n];
    }
    f32x4 s1v[2], s2v[2];
    for (int i = 0; i < 2; ++i) { s1v[i] = vz; s2v[i] = vz; }
    for (int i = 0; i < 2; ++i)
        for (int j = 0; j < 8; ++j)
            for (int rg = 0; rg < 4; ++rg) {
                int row = m0 + wm + i * 16 + l4 * 4 + rg;
                int n = wn + j * 16 + l15;
                float z = acc[i][j][rg] + bn[j];
                z = z > 0.f ? z : 0.f;
                float v = bf2f(A[(size_t)row * 512 + n]) + z;
                acc[i][j][rg] = v;
                s1v[i][rg] += v;
                s2v[i][rg] += v * v;
            }
    for (int i = 0; i < 2; ++i)
        for (int rg = 0; rg < 4; ++rg) {
            float a = s1v[i][rg], c = s2v[i][rg];
            for (int off = 1; off < 16; off <<= 1) {
                a += __shfl_xor(a, off);
                c += __shfl_xor(c, off);
            }
            s1v[i][rg] = a; s2v[i][rg] = c;
        }
    if (l15 == 0)
        for (int i = 0; i < 2; ++i)
            for (int rg = 0; rg < 4; ++rg) {
                int rl = wm + i * 16 + l4 * 4 + rg;
                part[rl][w & 3][0] = s1v[i][rg];
                part[rl][w & 3][1] = s2v[i][rg];
            }
    __syncthreads();
    if (tid < 64) {
        float a = 0.f, c = 0.f;
        for (int q = 0; q < 4; ++q) { a += part[tid][q][0]; c += part[tid][q][1]; }
        float mu = a * (1.f / 512.f);
        float var = c * (1.f / 512.f) - mu * mu;
        stats[tid][0] = mu;
        stats[tid][1] = rsqrtf(var + 1e-5f);
    }
    __syncthreads();
    for (int i = 0; i < 2; ++i)
        for (int rg = 0; rg < 4; ++rg) {
            int rl = wm + i * 16 + l4 * 4 + rg;
            float mu = stats[rl][0], rs = stats[rl][1];
            for (int j = 0; j < 8; ++j) {
                int n = wn + j * 16 + l15;
                out[(size_t)(m0 + rl) * 512 + n] = (acc[i][j][rg] - mu) * rs * gv[j] + bv2[j];
            }
        }
}

extern "C" void kernel_launch(void* const* d_in, const int* in_sizes, int n_in,
                              void* d_out, int out_size, void* d_ws, size_t ws_size,
                              hipStream_t stream) {
    const float* Q  = (const float*)d_in[0];
    const float* K  = (const float*)d_in[1];
    const float* Wq = (const float*)d_in[2];
    const float* bq = (const float*)d_in[3];
    const float* Wk = (const float*)d_in[4];
    const float* bk = (const float*)d_in[5];
    const float* Wv = (const float*)d_in[6];
    const float* bv = (const float*)d_in[7];
    const float* Wo = (const float*)d_in[8];
    const float* bo = (const float*)d_in[9];
    const float* g0 = (const float*)d_in[10];
    const float* b0 = (const float*)d_in[11];
    const float* g1 = (const float*)d_in[12];
    const float* b1 = (const float*)d_in[13];
    float* out = (float*)d_out;

    const size_t SZ_BF = (size_t)16384 * 512 * 2;
    const size_t SZ_W  = (size_t)512 * 512 * 2;
    char* p = (char*)d_ws;
    unsigned short* Wqt = (unsigned short*)p; p += SZ_W;
    unsigned short* Wkt = (unsigned short*)p; p += SZ_W;
    unsigned short* Wvt = (unsigned short*)p; p += SZ_W;
    unsigned short* Wot = (unsigned short*)p; p += SZ_W;
    unsigned short* Qsc = (unsigned short*)p; p += SZ_BF;   // Q proj, pre-scaled log2e/sqrt(512)
    unsigned short* Kp  = (unsigned short*)p; p += SZ_BF;
    unsigned short* VpT = (unsigned short*)p; p += SZ_BF;
    unsigned short* A1b = (unsigned short*)p; p += SZ_BF;   // attn out (pre-LN0)
    unsigned short* X0b = (unsigned short*)p; p += SZ_BF;   // LN0 out

    k_transpose4<<<256, 256, 0, stream>>>(Wq, Wk, Wv, Wo, Wqt, Wkt, Wvt, Wot);

    const float scale2 = 0.063758718f;  // log2(e)/sqrt(512)
    k_gemmF<0><<<512, 256, 0, stream>>>(Q, Wqt, bq, Qsc, scale2);
    k_gemmF<0><<<512, 256, 0, stream>>>(K, Wkt, bk, Kp, 1.0f);
    k_gemmF<1><<<512, 256, 0, stream>>>(K, Wvt, bv, VpT, 1.0f);

    k_attn32<<<1024, 256, 0, stream>>>(Qsc, Kp, VpT, A1b);

    k_ln_bf<<<4096, 256, 0, stream>>>(A1b, X0b, g0, b0);
    k_gemm2ln<<<256, 512, 0, stream>>>(X0b, Wot, bo, g1, b1, out);
}

// Round 7
// 142.543 us; speedup vs baseline: 1.0863x; 1.0849x over previous
//
#include <hip/hip_runtime.h>
#include <hip/hip_bf16.h>

typedef float f32x4 __attribute__((ext_vector_type(4)));
typedef float f32x16 __attribute__((ext_vector_type(16)));
typedef __bf16 bf16x8 __attribute__((ext_vector_type(8)));
typedef __bf16 bf16x4 __attribute__((ext_vector_type(4)));

#define MFMA(a, b, c) __builtin_amdgcn_mfma_f32_16x16x32_bf16(a, b, c, 0, 0, 0)
#define MFMA32(a, b, c) __builtin_amdgcn_mfma_f32_32x32x16_bf16(a, b, c, 0, 0, 0)
#define AS1 __attribute__((address_space(1)))
#define AS3 __attribute__((address_space(3)))

__device__ __forceinline__ void gload16(const void* g, void* l) {
    __builtin_amdgcn_global_load_lds((const AS1 unsigned int*)g, (AS3 unsigned int*)l, 16, 0, 0);
}

__device__ __forceinline__ unsigned short f2bf(float f) {
    union { float f; unsigned u; } x{f};
    unsigned r = x.u + 0x7FFFu + ((x.u >> 16) & 1u);
    return (unsigned short)(r >> 16);
}
__device__ __forceinline__ float bf2f(unsigned short u) {
    union { unsigned u; float f; } x; x.u = ((unsigned)u) << 16; return x.f;
}
__device__ __forceinline__ unsigned pkbf(float a, float b) {
    union { __bf16 h[2]; unsigned u; } r;
    r.h[0] = (__bf16)a; r.h[1] = (__bf16)b;
    return r.u;
}

// exp2 + pack + cross-lane P-fragment assembly for one 32-q half (verified in R6)
__device__ __forceinline__ void softmax_pack(const f32x16& s0, const f32x16& s1,
                                             float& ls, int hi, bf16x8* pf) {
    unsigned We[8], Wf[8];
    #pragma unroll
    for (int g = 0; g < 4; ++g) {
        float e0 = __builtin_amdgcn_exp2f(s0[4 * g + 0]);
        float e1 = __builtin_amdgcn_exp2f(s0[4 * g + 1]);
        float e2 = __builtin_amdgcn_exp2f(s0[4 * g + 2]);
        float e3 = __builtin_amdgcn_exp2f(s0[4 * g + 3]);
        float f0 = __builtin_amdgcn_exp2f(s1[4 * g + 0]);
        float f1 = __builtin_amdgcn_exp2f(s1[4 * g + 1]);
        float f2 = __builtin_amdgcn_exp2f(s1[4 * g + 2]);
        float f3 = __builtin_amdgcn_exp2f(s1[4 * g + 3]);
        ls += ((e0 + e1) + (e2 + e3)) + ((f0 + f1) + (f2 + f3));
        We[2 * g + 0] = pkbf(e0, e1); We[2 * g + 1] = pkbf(e2, e3);
        Wf[2 * g + 0] = pkbf(f0, f1); Wf[2 * g + 1] = pkbf(f2, f3);
    }
    #pragma unroll
    for (int src = 0; src < 2; ++src) {
        const unsigned* W = src == 0 ? We : Wf;
        #pragma unroll
        for (int k2 = 0; k2 < 2; ++k2) {
            unsigned A0 = W[4 * k2 + 0], A1 = W[4 * k2 + 1];
            unsigned B0 = W[4 * k2 + 2], B1 = W[4 * k2 + 3];
            unsigned cross0 = __shfl_xor(hi ? A0 : B0, 32);
            unsigned cross1 = __shfl_xor(hi ? A1 : B1, 32);
            union { unsigned w[4]; bf16x8 v; } r;
            r.w[0] = hi ? cross0 : A0;
            r.w[1] = hi ? cross1 : A1;
            r.w[2] = hi ? B0 : cross0;
            r.w[3] = hi ? B1 : cross1;
            pf[src * 2 + k2] = r.v;
        }
    }
}

// ---------- all 4 weight transposes in one launch ----------
__global__ __launch_bounds__(256) void k_transpose4(const float* W0, const float* W1,
                                                    const float* W2, const float* W3,
                                                    unsigned short* T0, unsigned short* T1,
                                                    unsigned short* T2, unsigned short* T3) {
    __shared__ float T[64][65];
    int sel = blockIdx.x >> 6, tile = blockIdx.x & 63;
    const float* W = sel == 0 ? W0 : sel == 1 ? W1 : sel == 2 ? W2 : W3;
    unsigned short* Wt = sel == 0 ? T0 : sel == 1 ? T1 : sel == 2 ? T2 : T3;
    int k0 = (tile >> 3) * 64, n0 = (tile & 7) * 64;
    int tid = threadIdx.x;
    for (int it = 0; it < 16; ++it) {
        int id = it * 256 + tid;
        int r = id >> 6, c = id & 63;
        T[r][c] = W[(k0 + r) * 512 + n0 + c];
    }
    __syncthreads();
    for (int it = 0; it < 16; ++it) {
        int id = it * 256 + tid;
        int r = id >> 6, c = id & 63;
        Wt[(n0 + r) * 512 + k0 + c] = f2bf(T[c][r]);
    }
}

// ---------- merged Q/K/V projections: 3 x (16384x512x512) in one dispatch ----------
// sel 0: Qsc = bf16((Q Wq + bq) * scale2); sel 1: Kp = bf16(K Wk + bk);
// sel 2: VpT[b][d][key] = bf16(K Wv + bv) transposed.
__global__ __launch_bounds__(256) void k_proj(const float* __restrict__ Qf,
                                              const float* __restrict__ Kf,
                                              const unsigned short* __restrict__ Wqt,
                                              const unsigned short* __restrict__ Wkt,
                                              const unsigned short* __restrict__ Wvt,
                                              const float* __restrict__ bq,
                                              const float* __restrict__ bk,
                                              const float* __restrict__ bv,
                                              unsigned short* __restrict__ Qsc,
                                              unsigned short* __restrict__ Kpo,
                                              unsigned short* __restrict__ VpT,
                                              float scale2) {
    __shared__ __align__(16) float AbS[2][4096];           // 2 x 128 x 32 f32
    __shared__ __align__(16) unsigned short BbS[2][4096];  // 2 x 128 x 32 bf16
    const int tid = threadIdx.x;
    const int lane = tid & 63, w = tid >> 6;
    const int sel = blockIdx.x >> 9;
    int ib = blockIdx.x & 511;
    const float* A = sel == 0 ? Qf : Kf;
    const unsigned short* Bt = sel == 0 ? Wqt : sel == 1 ? Wkt : Wvt;
    const float* bias = sel == 0 ? bq : sel == 1 ? bk : bv;
    const float scale = sel == 0 ? scale2 : 1.0f;
    const int mt = (ib & 7) | ((ib >> 5) << 3), nt = (ib >> 3) & 3;  // XCD swizzle
    const int m0 = mt * 128, n0 = nt * 128;
    const int wm = (w >> 1) * 64, wn = (w & 1) * 64;
    const int l15 = lane & 15, l4 = lane >> 4;

    const f32x4 vz = {0.f, 0.f, 0.f, 0.f};
    f32x4 acc[4][4];
    for (int i = 0; i < 4; ++i)
        for (int j = 0; j < 4; ++j) acc[i][j] = vz;

    const float* Abase = A + (size_t)m0 * 512;
    const unsigned short* Bbase = Bt + (size_t)n0 * 512;

    auto STAGE = [&](int ks, int p) {
        int kk = ks * 32;
        #pragma unroll
        for (int it = 0; it < 4; ++it) {
            int id = it * 256 + tid;
            int r = id >> 3, cc = id & 7, g = cc ^ (r & 7);
            gload16(Abase + r * 512 + kk + g * 4, &AbS[p][(it * 256 + w * 64) * 4]);
        }
        #pragma unroll
        for (int it = 0; it < 2; ++it) {
            int id = it * 256 + tid;
            int r = id >> 2, x = id & 3, c = x ^ (r & 3);
            gload16(Bbase + r * 512 + kk + c * 8, &BbS[p][(it * 256 + w * 64) * 8]);
        }
    };

    STAGE(0, 0);
    __syncthreads();
    for (int ks = 0; ks < 16; ++ks) {
        int p = ks & 1;
        if (ks < 15) STAGE(ks + 1, p ^ 1);
        bf16x8 af[4], bfr[4];
        #pragma unroll
        for (int i = 0; i < 4; ++i) {
            int r = wm + i * 16 + l15;
            int pc0 = (2 * l4) ^ (r & 7);
            const float* Af = &AbS[p][r * 32];
            f32x4 a0 = *(const f32x4*)(Af + pc0 * 4);
            f32x4 a1 = *(const f32x4*)(Af + (pc0 ^ 1) * 4);
            af[i] = bf16x8{(__bf16)a0[0], (__bf16)a0[1], (__bf16)a0[2], (__bf16)a0[3],
                           (__bf16)a1[0], (__bf16)a1[1], (__bf16)a1[2], (__bf16)a1[3]};
        }
        #pragma unroll
        for (int j = 0; j < 4; ++j) {
            int r = wn + j * 16 + l15, pc = l4 ^ (r & 3);
            bfr[j] = *(const bf16x8*)&BbS[p][r * 32 + pc * 8];
        }
        __builtin_amdgcn_s_setprio(1);
        #pragma unroll
        for (int i = 0; i < 4; ++i)
            #pragma unroll
            for (int j = 0; j < 4; ++j)
                acc[i][j] = MFMA(af[i], bfr[j], acc[i][j]);
        __builtin_amdgcn_s_setprio(0);
        __syncthreads();
    }

    float bn[4];
    for (int j = 0; j < 4; ++j) bn[j] = bias[n0 + wn + j * 16 + l15];

    if (sel < 2) {
        unsigned short* out = sel == 0 ? Qsc : Kpo;
        for (int i = 0; i < 4; ++i)
            for (int j = 0; j < 4; ++j)
                for (int rg = 0; rg < 4; ++rg) {
                    int m = m0 + wm + i * 16 + l4 * 4 + rg;
                    int n = n0 + wn + j * 16 + l15;
                    out[(size_t)m * 512 + n] = f2bf((acc[i][j][rg] + bn[j]) * scale);
                }
    } else {
        // VpT[b][d][key] via per-wave LDS transpose (reuse A staging region)
        unsigned short* T = (unsigned short*)&AbS[0][0] + w * 4096;
        __syncthreads();
        for (int i = 0; i < 4; ++i)
            for (int j = 0; j < 4; ++j)
                for (int rg = 0; rg < 4; ++rg) {
                    int ml = i * 16 + l4 * 4 + rg;   // key-local
                    int nl = j * 16 + l15;           // d-local
                    int pc = (ml >> 3) ^ (nl & 7);
                    T[nl * 64 + pc * 8 + (ml & 7)] = f2bf(acc[i][j][rg] + bn[j]);
                }
        int b = (m0 + wm) >> 10;
        int key0 = (m0 + wm) & 1023;
        for (int it = 0; it < 8; ++it) {
            int ch = it * 64 + lane;
            int nl = ch >> 3, c = ch & 7, pc = c ^ (nl & 7);
            int4 v = *(const int4*)&T[nl * 64 + pc * 8];
            int d = n0 + wn + nl;
            *(int4*)(VpT + ((size_t)b * 512 + d) * 1024 + key0 + c * 8) = v;
        }
    }
}

// ---------- flash attention: 64 q-rows/wave, 2-wave blocks, in-register P ----------
// Qs pre-scaled by log2(e)/sqrt(512); O1b = bf16(Qs*invscale + softmax2(Qs K^T) V)
__global__ __launch_bounds__(128, 2) void k_attn64(const unsigned short* __restrict__ Qs,
                                                   const unsigned short* __restrict__ Kp,
                                                   const unsigned short* __restrict__ VpT,
                                                   unsigned short* __restrict__ O1b) {
    // u16: K dbuf [0,8192) | V dbuf [8192,16384)
    __shared__ __align__(16) unsigned short sm[16384];
    const int tid = threadIdx.x, lane = tid & 63, w = tid >> 6;  // w in {0,1}
    const int l31 = lane & 31, hi = lane >> 5;
    int i = blockIdx.x;
    const int xcd = i & 7, r2 = i >> 3;
    const int bhl = r2 & 15, qt = r2 >> 4;      // 16 bh per XCD, 8 q-tiles of 128
    const int bh = xcd * 16 + bhl;
    const int h = bh & 7, b = bh >> 3;
    const int q0 = b * 1024 + qt * 128 + w * 64;
    const int kv0 = (qt * 3 + bhl * 5) & 15;    // stagger kv start (sum-associative)

    const unsigned short* Ksrc = Kp + (size_t)(b * 1024) * 512 + h * 64;
    const unsigned short* Vsrc = VpT + (size_t)(b * 512 + h * 64) * 1024;
    const unsigned short* qptrA = Qs + (size_t)(q0 + l31) * 512 + h * 64;
    const unsigned short* qptrB = qptrA + (size_t)32 * 512;

    bf16x8 qfA[4], qfB[4];
    #pragma unroll
    for (int ks = 0; ks < 4; ++ks) {
        qfA[ks] = *(const bf16x8*)(qptrA + ks * 16 + hi * 8);
        qfB[ks] = *(const bf16x8*)(qptrB + ks * 16 + hi * 8);
    }

    f32x16 accA0, accA1, accB0, accB1;
    #pragma unroll
    for (int r = 0; r < 16; ++r) { accA0[r] = 0.f; accA1[r] = 0.f; accB0[r] = 0.f; accB1[r] = 0.f; }
    float lsA = 0.f, lsB = 0.f;

    auto STAGE = [&](int j, int p) {
        int t = (j + kv0) & 15;
        #pragma unroll
        for (int it = 0; it < 4; ++it) {
            int id = it * 128 + tid;
            int r = id >> 3, x = id & 7, c = x ^ (r & 7);
            unsigned short* kb = sm + p * 4096 + (it * 128 + w * 64) * 8;
            gload16(Ksrc + (size_t)(t * 64 + r) * 512 + c * 8, kb);
            gload16(Vsrc + (size_t)r * 1024 + t * 64 + c * 8, kb + 8192);
        }
    };

    STAGE(0, 0);
    __syncthreads();
    const int rsw = l31 & 7;
    for (int it2 = 0; it2 < 16; ++it2) {
        int p = it2 & 1;
        if (it2 < 15) STAGE(it2 + 1, p ^ 1);
        const unsigned short* Kl = sm + p * 4096;
        const unsigned short* Vl = sm + 8192 + p * 4096;

        // S^T = mfma32(K, Q) for both q-halves; kf shared (transient)
        f32x16 s0a, s1a, s0b, s1b;
        #pragma unroll
        for (int r = 0; r < 16; ++r) { s0a[r] = 0.f; s1a[r] = 0.f; s0b[r] = 0.f; s1b[r] = 0.f; }
        __builtin_amdgcn_s_setprio(1);
        #pragma unroll
        for (int ks = 0; ks < 4; ++ks) {
            int c = (2 * ks + hi) ^ rsw;
            bf16x8 kf0 = *(const bf16x8*)&Kl[l31 * 64 + c * 8];
            bf16x8 kf1 = *(const bf16x8*)&Kl[(32 + l31) * 64 + c * 8];
            s0a = MFMA32(kf0, qfA[ks], s0a);
            s1a = MFMA32(kf1, qfA[ks], s1a);
            s0b = MFMA32(kf0, qfB[ks], s0b);
            s1b = MFMA32(kf1, qfB[ks], s1b);
        }
        __builtin_amdgcn_s_setprio(0);

        bf16x8 pfA[4], pfB[4];
        softmax_pack(s0a, s1a, lsA, hi, pfA);
        softmax_pack(s0b, s1b, lsB, hi, pfB);

        // PV: O^T = mfma32(V^T, P^T); vf shared across halves (transient)
        __builtin_amdgcn_s_setprio(1);
        #pragma unroll
        for (int ks = 0; ks < 4; ++ks) {
            int c = (2 * ks + hi) ^ rsw;
            bf16x8 vf0 = *(const bf16x8*)&Vl[l31 * 64 + c * 8];
            bf16x8 vf1 = *(const bf16x8*)&Vl[(32 + l31) * 64 + c * 8];
            accA0 = MFMA32(vf0, pfA[ks], accA0);
            accA1 = MFMA32(vf1, pfA[ks], accA1);
            accB0 = MFMA32(vf0, pfB[ks], accB0);
            accB1 = MFMA32(vf1, pfB[ks], accB1);
        }
        __builtin_amdgcn_s_setprio(0);
        __syncthreads();
    }

    const float invscale = 15.6841306f;  // sqrt(512)/log2(e)
    {
        float l = lsA + __shfl_xor(lsA, 32);
        float linv = 1.0f / l;
        unsigned short* orow = O1b + (size_t)(q0 + l31) * 512 + h * 64;
        #pragma unroll
        for (int g = 0; g < 4; ++g) {
            int d0 = 8 * g + 4 * hi;
            bf16x4 qres = *(const bf16x4*)(qptrA + d0);
            bf16x4 ov;
            for (int j = 0; j < 4; ++j)
                ov[j] = (__bf16)((float)qres[j] * invscale + accA0[4 * g + j] * linv);
            *(bf16x4*)(orow + d0) = ov;
            int d1 = 32 + d0;
            bf16x4 qres1 = *(const bf16x4*)(qptrA + d1);
            bf16x4 ov1;
            for (int j = 0; j < 4; ++j)
                ov1[j] = (__bf16)((float)qres1[j] * invscale + accA1[4 * g + j] * linv);
            *(bf16x4*)(orow + d1) = ov1;
        }
    }
    {
        float l = lsB + __shfl_xor(lsB, 32);
        float linv = 1.0f / l;
        unsigned short* orow = O1b + (size_t)(q0 + 32 + l31) * 512 + h * 64;
        #pragma unroll
        for (int g = 0; g < 4; ++g) {
            int d0 = 8 * g + 4 * hi;
            bf16x4 qres = *(const bf16x4*)(qptrB + d0);
            bf16x4 ov;
            for (int j = 0; j < 4; ++j)
                ov[j] = (__bf16)((float)qres[j] * invscale + accB0[4 * g + j] * linv);
            *(bf16x4*)(orow + d0) = ov;
            int d1 = 32 + d0;
            bf16x4 qres1 = *(const bf16x4*)(qptrB + d1);
            bf16x4 ov1;
            for (int j = 0; j < 4; ++j)
                ov1[j] = (__bf16)((float)qres1[j] * invscale + accB1[4 * g + j] * linv);
            *(bf16x4*)(orow + d1) = ov1;
        }
    }
}

// ---------- LayerNorm bf16 in -> bf16 out ----------
__global__ __launch_bounds__(256) void k_ln_bf(const unsigned short* __restrict__ in,
                                               unsigned short* __restrict__ outb,
                                               const float* __restrict__ g,
                                               const float* __restrict__ bt) {
    int row = blockIdx.x * 4 + (threadIdx.x >> 6);
    int lane = threadIdx.x & 63;
    const unsigned short* x = in + (size_t)row * 512 + lane * 8;
    bf16x8 v = *(const bf16x8*)x;
    float f[8];
    for (int j = 0; j < 8; ++j) f[j] = (float)v[j];
    float s1 = 0.f, s2 = 0.f;
    for (int j = 0; j < 8; ++j) { s1 += f[j]; s2 += f[j] * f[j]; }
    for (int off = 32; off; off >>= 1) {
        s1 += __shfl_xor(s1, off);
        s2 += __shfl_xor(s2, off);
    }
    float mu = s1 * (1.f / 512.f);
    float var = s2 * (1.f / 512.f) - mu * mu;
    float rs = rsqrtf(var + 1e-5f);
    float4 ga = *(const float4*)(g + lane * 8), gb = *(const float4*)(g + lane * 8 + 4);
    float4 ba = *(const float4*)(bt + lane * 8), bb = *(const float4*)(bt + lane * 8 + 4);
    float gg[8] = {ga.x, ga.y, ga.z, ga.w, gb.x, gb.y, gb.z, gb.w};
    float bv[8] = {ba.x, ba.y, ba.z, ba.w, bb.x, bb.y, bb.z, bb.w};
    bf16x8 y;
    for (int j = 0; j < 8; ++j) y[j] = (__bf16)((f[j] - mu) * rs * gg[j] + bv[j]);
    *(bf16x8*)(outb + (size_t)row * 512 + lane * 8) = y;
}

// ---------- fused FFN GEMM + residual + final LayerNorm ----------
__global__ __launch_bounds__(512, 2) void k_gemm2ln(const unsigned short* __restrict__ A,
                                                    const unsigned short* __restrict__ Bt,
                                                    const float* __restrict__ bias,
                                                    const float* __restrict__ g1,
                                                    const float* __restrict__ b1,
                                                    float* __restrict__ out) {
    __shared__ __align__(16) unsigned short Ab[2][2048];    // 64 x 32
    __shared__ __align__(16) unsigned short Bb[2][16384];   // 512 x 32
    __shared__ float part[64][4][2];
    __shared__ float stats[64][2];
    const int tid = threadIdx.x, lane = tid & 63, w = tid >> 6;
    const int l15 = lane & 15, l4 = lane >> 4;
    const int m0 = blockIdx.x * 64;
    const int wm = (w >> 2) * 32, wn = (w & 3) * 128;

    const f32x4 vz = {0.f, 0.f, 0.f, 0.f};
    f32x4 acc[2][8];
    for (int i = 0; i < 2; ++i)
        for (int j = 0; j < 8; ++j) acc[i][j] = vz;

    const unsigned short* Abase = A + (size_t)m0 * 512;

    auto STAGE = [&](int ks, int p) {
        int kk = ks * 32;
        for (int it = 0; it < 4; ++it) {
            int id = it * 512 + tid;
            int r = id >> 2, x = id & 3, c = x ^ (r & 3);
            gload16(Bt + r * 512 + kk + c * 8, &Bb[p][(it * 512 + w * 64) * 8]);
        }
        if (w < 4) {
            int id = w * 64 + lane;
            int r = id >> 2, x = id & 3, c = x ^ (r & 3);
            gload16(Abase + r * 512 + kk + c * 8, &Ab[p][(w * 64) * 8]);
        }
    };

    STAGE(0, 0);
    __syncthreads();
    for (int ks = 0; ks < 16; ++ks) {
        int p = ks & 1;
        if (ks < 15) STAGE(ks + 1, p ^ 1);
        bf16x8 af[2], bfr[8];
        for (int i = 0; i < 2; ++i) {
            int r = wm + i * 16 + l15, pc = l4 ^ (r & 3);
            af[i] = *(const bf16x8*)&Ab[p][r * 32 + pc * 8];
        }
        for (int j = 0; j < 8; ++j) {
            int r = wn + j * 16 + l15, pc = l4 ^ (r & 3);
            bfr[j] = *(const bf16x8*)&Bb[p][r * 32 + pc * 8];
        }
        __builtin_amdgcn_s_setprio(1);
        for (int i = 0; i < 2; ++i)
            for (int j = 0; j < 8; ++j)
                acc[i][j] = MFMA(af[i], bfr[j], acc[i][j]);
        __builtin_amdgcn_s_setprio(0);
        __syncthreads();
    }

    float bn[8], gv[8], bv2[8];
    for (int j = 0; j < 8; ++j) {
        int n = wn + j * 16 + l15;
        bn[j] = bias[n]; gv[j] = g1[n]; bv2[j] = b1[n];
    }
    f32x4 s1v[2], s2v[2];
    for (int i = 0; i < 2; ++i) { s1v[i] = vz; s2v[i] = vz; }
    for (int i = 0; i < 2; ++i)
        for (int j = 0; j < 8; ++j)
            for (int rg = 0; rg < 4; ++rg) {
                int row = m0 + wm + i * 16 + l4 * 4 + rg;
                int n = wn + j * 16 + l15;
                float z = acc[i][j][rg] + bn[j];
                z = z > 0.f ? z : 0.f;
                float v = bf2f(A[(size_t)row * 512 + n]) + z;
                acc[i][j][rg] = v;
                s1v[i][rg] += v;
                s2v[i][rg] += v * v;
            }
    for (int i = 0; i < 2; ++i)
        for (int rg = 0; rg < 4; ++rg) {
            float a = s1v[i][rg], c = s2v[i][rg];
            for (int off = 1; off < 16; off <<= 1) {
                a += __shfl_xor(a, off);
                c += __shfl_xor(c, off);
            }
            s1v[i][rg] = a; s2v[i][rg] = c;
        }
    if (l15 == 0)
        for (int i = 0; i < 2; ++i)
            for (int rg = 0; rg < 4; ++rg) {
                int rl = wm + i * 16 + l4 * 4 + rg;
                part[rl][w & 3][0] = s1v[i][rg];
                part[rl][w & 3][1] = s2v[i][rg];
            }
    __syncthreads();
    if (tid < 64) {
        float a = 0.f, c = 0.f;
        for (int q = 0; q < 4; ++q) { a += part[tid][q][0]; c += part[tid][q][1]; }
        float mu = a * (1.f / 512.f);
        float var = c * (1.f / 512.f) - mu * mu;
        stats[tid][0] = mu;
        stats[tid][1] = rsqrtf(var + 1e-5f);
    }
    __syncthreads();
    for (int i = 0; i < 2; ++i)
        for (int rg = 0; rg < 4; ++rg) {
            int rl = wm + i * 16 + l4 * 4 + rg;
            float mu = stats[rl][0], rs = stats[rl][1];
            for (int j = 0; j < 8; ++j) {
                int n = wn + j * 16 + l15;
                out[(size_t)(m0 + rl) * 512 + n] = (acc[i][j][rg] - mu) * rs * gv[j] + bv2[j];
            }
        }
}

extern "C" void kernel_launch(void* const* d_in, const int* in_sizes, int n_in,
                              void* d_out, int out_size, void* d_ws, size_t ws_size,
                              hipStream_t stream) {
    const float* Q  = (const float*)d_in[0];
    const float* K  = (const float*)d_in[1];
    const float* Wq = (const float*)d_in[2];
    const float* bq = (const float*)d_in[3];
    const float* Wk = (const float*)d_in[4];
    const float* bk = (const float*)d_in[5];
    const float* Wv = (const float*)d_in[6];
    const float* bv = (const float*)d_in[7];
    const float* Wo = (const float*)d_in[8];
    const float* bo = (const float*)d_in[9];
    const float* g0 = (const float*)d_in[10];
    const float* b0 = (const float*)d_in[11];
    const float* g1 = (const float*)d_in[12];
    const float* b1 = (const float*)d_in[13];
    float* out = (float*)d_out;

    const size_t SZ_BF = (size_t)16384 * 512 * 2;
    const size_t SZ_W  = (size_t)512 * 512 * 2;
    char* p = (char*)d_ws;
    unsigned short* Wqt = (unsigned short*)p; p += SZ_W;
    unsigned short* Wkt = (unsigned short*)p; p += SZ_W;
    unsigned short* Wvt = (unsigned short*)p; p += SZ_W;
    unsigned short* Wot = (unsigned short*)p; p += SZ_W;
    unsigned short* Qsc = (unsigned short*)p; p += SZ_BF;   // Q proj, pre-scaled log2e/sqrt(512)
    unsigned short* Kp  = (unsigned short*)p; p += SZ_BF;
    unsigned short* VpT = (unsigned short*)p; p += SZ_BF;
    unsigned short* A1b = (unsigned short*)p; p += SZ_BF;   // attn out (pre-LN0)
    unsigned short* X0b = (unsigned short*)p; p += SZ_BF;   // LN0 out

    k_transpose4<<<256, 256, 0, stream>>>(Wq, Wk, Wv, Wo, Wqt, Wkt, Wvt, Wot);

    const float scale2 = 0.063758718f;  // log2(e)/sqrt(512)
    k_proj<<<1536, 256, 0, stream>>>(Q, K, Wqt, Wkt, Wvt, bq, bk, bv, Qsc, Kp, VpT, scale2);

    k_attn64<<<1024, 128, 0, stream>>>(Qsc, Kp, VpT, A1b);

    k_ln_bf<<<4096, 256, 0, stream>>>(A1b, X0b, g0, b0);
    k_gemm2ln<<<256, 512, 0, stream>>>(X0b, Wot, bo, g1, b1, out);
}